// Round 6
// baseline (159.282 us; speedup 1.0000x reference)
//
#include <hip/hip_runtime.h>
#include <math.h>

#define B_      16
#define K_      200000
#define N_      40
#define TPB     256
#define TT      512                          // elements per staged tile
#define CBX     48                           // chunks per batch
#define CHUNK   4168                         // even, 16B-aligned slices; 48*4168 >= K_
#define NBLOCKS (CBX * B_)                   // 768 = exactly 3 blocks/CU
#define NE      (2 * N_)                     // 80 endpoints
#define NACC    7
#define PACC    8

// ws: [0, NBLOCKS*PACC*4) per-block partials (24,576 B). Nothing else.

// async global->LDS DMA, 16B per lane; dest = wave-uniform base + lane*16
__device__ __forceinline__ void gload16(const float4* g, float4* l) {
    __builtin_amdgcn_global_load_lds(
        (const __attribute__((address_space(1))) unsigned int*)g,
        (__attribute__((address_space(3))) unsigned int*)l,
        16, 0, 0);
}

// counted vmem wait (keeps N DMAs in flight) + scheduling fence (rule #18)
#define WAITV(N) do { asm volatile("s_waitcnt vmcnt(" #N ")" ::: "memory"); \
                      __builtin_amdgcn_sched_barrier(0); } while (0)
// raw workgroup barrier (does NOT drain vmcnt, unlike __syncthreads)
#define RBAR()   do { __builtin_amdgcn_sched_barrier(0); \
                      __builtin_amdgcn_s_barrier(); \
                      __builtin_amdgcn_sched_barrier(0); } while (0)
// LDS-only barrier for the table-build prologue (lgkm drain, vmcnt untouched)
#define LBAR()   do { asm volatile("s_waitcnt lgkmcnt(0)" ::: "memory"); \
                      __builtin_amdgcn_sched_barrier(0); \
                      __builtin_amdgcn_s_barrier(); \
                      __builtin_amdgcn_sched_barrier(0); } while (0)

__device__ __forceinline__ void elem_accum(
    const float c, const float pl, const float pr,
    const float x0, const float x1,
    const float p0, const float p1,
    const float y0, const float y1,
    const float lg,
    const int base, const int end,
    const float* __restrict__ s_bp,
    const float4* __restrict__ s_tab,          // [0..79]=at, [80..160]=gap
    float& f0, float& f1, float& f2, float& f3,
    float& f4, float& f5, float& f6)
{
    const float EPS = 1.1920928955078125e-7f;  // FLT_EPSILON

    // ---- match: pos = #bp <= c; in-range bp are contiguous [base,end) ----
    int pos = base; bool eq = false;
    for (int i = base; i < end; ++i) {           // block-uniform bounds
        const float v = s_bp[i];                 // broadcast read
        pos += (v <= c) ? 1 : 0;
        eq  |= (v == c);
    }
    const int idx = eq ? (pos - 1) : (NE + pos);
    const float4 sg = s_tab[idx];

    const float tl = sg.x, tr = sg.y;
    const int conf_t = (int)sg.z;                // 0 when unmatched
    const float lt0 = (c - tl) * 256.0f;
    const float lt1 = (tr - c) * 256.0f;

    // ---- iou(loc, loc_t) ----
    const float inter = fminf(pl, lt0) + fminf(pr, lt1);
    const float uni   = pl + pr + (lt0 + lt1) - inter;
    const float iou   = __fdividef(inter, fmaxf(uni, EPS));
    const int pconf_t = (iou < 0.5f) ? 0 : conf_t;

    const float posf = (conf_t > 0) ? 1.0f : 0.0f;
    const float ppf  = (pconf_t > 0) ? 1.0f : 0.0f;

    // GIoU (pos only)
    const float ac   = fmaxf(pl, lt0) + fmaxf(pr, lt1);
    const float giou = iou - __fdividef(ac - uni, fmaxf(ac, EPS));
    f0 += (1.0f - giou) * posf;

    // prop loc L1 (prop-pos only)
    const float prop_w = pl + pr;
    const float rw = __fdividef(1.0f, 0.5f * prop_w);
    const float plt0 = (lt0 - pl) * rw;
    const float plt1 = (lt1 - pr) * rw;
    f2 += (fabsf(p0 - plt0) + fabsf(p1 - plt1)) * ppf;

    // centerness BCE (pos only)
    const float cur0 = 0.5f * prop_w * p0 + pl;
    const float cur1 = 0.5f * prop_w * p1 + pr;
    const float inter2 = fminf(cur0, lt0) + fminf(cur1, lt1);
    const float uni2   = cur0 + cur1 + (lt0 + lt1) - inter2;
    const float iou2   = fmaxf(__fdividef(inter2, fmaxf(uni2, EPS)), 0.0f);
    const float bce = fmaxf(lg, 0.0f) - lg * iou2
                      + __logf(1.0f + __expf(-fabsf(lg)));
    f4 += bce * posf;

    // focal on conf (all elements)
    {
        const float xt = conf_t ? x1 : x0;
        const float xo = conf_t ? x0 : x1;
        const float pt = __fdividef(1.0f, 1.0f + __expf(xo - xt)) + 1e-6f;
        const float al = conf_t ? 0.75f : 0.25f;
        const float om = 1.0f - pt;
        f1 += -om * om * al * __logf(pt);
    }
    // focal on prop_conf (all elements)
    {
        const float xt = pconf_t ? y1 : y0;
        const float xo = pconf_t ? y0 : y1;
        const float pt = __fdividef(1.0f, 1.0f + __expf(xo - xt)) + 1e-6f;
        const float al = pconf_t ? 0.75f : 0.25f;
        const float om = 1.0f - pt;
        f3 += -om * om * al * __logf(pt);
    }

    f5 += posf;
    f6 += ppf;
}

__global__ __launch_bounds__(TPB) void msl_main(
    const float* __restrict__ loc,     // (B,K,2)
    const float* __restrict__ conf,    // (B,K,2)
    const float* __restrict__ ploc,    // (B,K,2)
    const float* __restrict__ pconf,   // (B,K,2)
    const float* __restrict__ center,  // (B,K,1)
    const float* __restrict__ priors,  // (K,1)
    const float* __restrict__ targets, // (B,N,3)
    char* __restrict__ ws)
{
    // double-buffered staging (40 KB)
    __shared__ float2 loc_s [2 * TT];
    __shared__ float2 conf_s[2 * TT];
    __shared__ float2 ploc_s[2 * TT];
    __shared__ float2 pcnf_s[2 * TT];
    __shared__ float  ctr_s [2 * TT];
    __shared__ float  pri_s [2 * TT];
    // tables (~4.5 KB)
    __shared__ float  tl0[N_], tr0[N_], lb0[N_], ar0[N_];
    __shared__ float  stl[N_], str[N_], slb[N_];
    __shared__ float  s_ep[NE];
    __shared__ float  s_bp[NE];
    __shared__ float4 s_tab[2 * NE + 1];
    __shared__ int    s_cnt[4];
    __shared__ float  s_redf[TPB / 64][NACC];

    const int b  = blockIdx.y;
    const int cb = blockIdx.x;
    const int t  = threadIdx.x;
    const int kb = cb * CHUNK;
    const int chunk = (kb + CHUNK < K_) ? CHUNK : (K_ - kb);
    const int kend  = kb + chunk;
    const int nfull = chunk / TT;              // 8 for every block

    const int bK  = b * K_;
    const int bK2 = bK * 2;

    // ---- stage a full tile: exactly 5 gload16 per thread, all waves equal ----
    auto stage = [&](int bufsel, int k0) {
        const int o = bufsel * TT;
        gload16((const float4*)(loc   + bK2 + 2 * k0) + t, (float4*)(loc_s  + o) + t);
        gload16((const float4*)(conf  + bK2 + 2 * k0) + t, (float4*)(conf_s + o) + t);
        gload16((const float4*)(ploc  + bK2 + 2 * k0) + t, (float4*)(ploc_s + o) + t);
        gload16((const float4*)(pconf + bK2 + 2 * k0) + t, (float4*)(pcnf_s + o) + t);
        if (t < 128)
            gload16((const float4*)(center + bK + k0) + t,       (float4*)(ctr_s + o) + t);
        else
            gload16((const float4*)(priors + k0) + (t - 128),    (float4*)(pri_s + o) + (t - 128));
    };

    // ======== prologue ========
    // targets loads first (wave0 only), then tile0 DMAs -> compiler's wait for
    // targets is a counted vmcnt that leaves the 5 DMAs in flight
    float ttl = 0.f, ttr = 0.f, tlb = 0.f;
    if (t < N_) {
        const float* tg = targets + (b * N_ + t) * 3;
        ttl = tg[0]; ttr = tg[1]; tlb = tg[2];
    }
    stage(0, kb);                               // tile 0 in flight

    // ---- table build (LDS-only barriers; never drains vmcnt) ----
    if (t < N_) {
        tl0[t] = ttl; tr0[t] = ttr; lb0[t] = tlb;
        ar0[t] = (ttr - ttl) * 256.0f;
    }
    LBAR();
    if (t < N_) {                               // stable rank-sort by area
        const float an = ar0[t];
        int r = 0;
        #pragma unroll
        for (int m = 0; m < N_; ++m) {
            const float am = ar0[m];
            r += (am < an) || (am == an && m < t);
        }
        stl[r] = tl0[t]; str[r] = tr0[t]; slb[r] = lb0[t];
    }
    if (t < NE) s_ep[t] = (t < N_) ? tl0[t] : tr0[t - N_];
    LBAR();
    if (t < NE) {                               // rank-sort endpoints
        const float v = s_ep[t];
        int r = 0;
        #pragma unroll
        for (int m = 0; m < NE; ++m) {
            const float vm = s_ep[m];
            r += (vm < v) || (vm == v && m < t);
        }
        s_bp[r] = v;
    }
    LBAR();
    if (t < 128) {                              // range ballot
        const float v = (t < NE) ? s_bp[t] : INFINITY;
        const float cmin = priors[kb];          // uniform -> s_load (lgkm)
        const float cmax = priors[kend - 1];
        const unsigned long long mlo = __ballot(v < cmin);
        const unsigned long long mhi = __ballot(v <= cmax);
        const int wv = t >> 6;
        if ((t & 63) == 0) {
            s_cnt[wv]     = __popcll(mlo);
            s_cnt[2 + wv] = __popcll(mhi);
        }
    }
    if (t < NE) {                               // point winners
        const float v = s_bp[t];
        int w = N_;
        for (int s = N_ - 1; s >= 0; --s)
            w = (stl[s] <= v && v <= str[s]) ? s : w;
        const bool ok = (w < N_);
        const int si = ok ? w : 0;
        s_tab[t] = ok ? make_float4(stl[si], str[si], slb[si], 1.0f)
                      : make_float4(0.f, 0.f, 0.f, 0.f);
    }
    if (t >= 128 && t < 128 + NE + 1) {         // gap winners
        const int g = t - 128;
        const float a  = g ? s_bp[g - 1] : -INFINITY;
        const float bb = (g < NE) ? s_bp[g] : INFINITY;
        int w = N_;
        for (int s = N_ - 1; s >= 0; --s)
            w = (stl[s] <= a && bb <= str[s]) ? s : w;
        const bool ok = (w < N_);
        const int si = ok ? w : 0;
        s_tab[NE + g] = ok ? make_float4(stl[si], str[si], slb[si], 1.0f)
                           : make_float4(0.f, 0.f, 0.f, 0.f);
    }
    LBAR();

    const int base = s_cnt[0] + s_cnt[1];
    const int end  = s_cnt[2] + s_cnt[3];

    stage(1, kb + TT);                          // tile 1 in flight

    float f0 = 0.f, f1 = 0.f, f2 = 0.f, f3 = 0.f, f4 = 0.f, f5 = 0.f, f6 = 0.f;

    // ======== main pipeline: compute tile while next tile's DMA in flight ====
    for (int tile = 0; tile < nfull; ++tile) {
        const int cur = tile & 1;
        const int o   = cur * TT;
        // drain stage(tile); keep stage(tile+1)'s 5 DMAs in flight
        if (tile + 1 < nfull) WAITV(5); else WAITV(0);
        RBAR();                                 // all waves' stage(tile) visible

        #pragma unroll
        for (int j = 0; j < 2; ++j) {
            const int kl = t + j * TPB;
            const float2 l  = loc_s [o + kl];
            const float2 cf = conf_s[o + kl];
            const float2 pp = ploc_s[o + kl];
            const float2 pc = pcnf_s[o + kl];
            elem_accum(pri_s[o + kl], l.x, l.y, cf.x, cf.y,
                       pp.x, pp.y, pc.x, pc.y, ctr_s[o + kl],
                       base, end, s_bp, s_tab,
                       f0, f1, f2, f3, f4, f5, f6);
        }
        RBAR();                                 // everyone done reading buf cur
        if (tile + 2 < nfull)
            stage(cur, kb + (tile + 2) * TT);   // refill freed buffer
    }

    // ======== tail (< TT elems): direct loads, vmcnt already 0 ========
    {
        const int k = kb + nfull * TT + t;
        if (k < kend) {
            const int i2 = bK2 + k * 2;
            const float2 l  = *(const float2*)(loc   + i2);
            const float2 cf = *(const float2*)(conf  + i2);
            const float2 pp = *(const float2*)(ploc  + i2);
            const float2 pc = *(const float2*)(pconf + i2);
            elem_accum(priors[k], l.x, l.y, cf.x, cf.y,
                       pp.x, pp.y, pc.x, pc.y, center[bK + k],
                       base, end, s_bp, s_tab,
                       f0, f1, f2, f3, f4, f5, f6);
        }
    }

    // ---- block reduction (f32 wave tree, f64 cross-wave) -> partials ----
    {
        float vals[NACC] = {f0, f1, f2, f3, f4, f5, f6};
        const int wave = t >> 6, lane = t & 63;
        #pragma unroll
        for (int q = 0; q < NACC; ++q) {
            float v = vals[q];
            #pragma unroll
            for (int off = 32; off > 0; off >>= 1)
                v += __shfl_down(v, off, 64);
            if (lane == 0) s_redf[wave][q] = v;
        }
    }
    __syncthreads();
    if (t == 0) {
        float* partials = (float*)ws;
        const int bid = b * CBX + cb;
        #pragma unroll
        for (int q = 0; q < NACC; ++q) {
            double s = 0.0;
            #pragma unroll
            for (int w2 = 0; w2 < TPB / 64; ++w2) s += (double)s_redf[w2][q];
            partials[bid * PACC + q] = (float)s;
        }
    }
}

__global__ __launch_bounds__(TPB) void msl_final(
    const float* __restrict__ partials, float* __restrict__ out)
{
    __shared__ double s_red[TPB / 64][NACC];
    double acc[NACC] = {0, 0, 0, 0, 0, 0, 0};
    for (int i = threadIdx.x; i < NBLOCKS; i += TPB) {
        #pragma unroll
        for (int q = 0; q < NACC; ++q)
            acc[q] += (double)partials[i * PACC + q];
    }
    const int wave = threadIdx.x >> 6, lane = threadIdx.x & 63;
    #pragma unroll
    for (int q = 0; q < NACC; ++q) {
        double v = acc[q];
        #pragma unroll
        for (int off = 32; off > 0; off >>= 1)
            v += __shfl_down(v, off, 64);
        if (lane == 0) s_red[wave][q] = v;
    }
    __syncthreads();
    if (threadIdx.x == 0) {
        double s[NACC];
        #pragma unroll
        for (int q = 0; q < NACC; ++q) {
            double v = 0.0;
            #pragma unroll
            for (int w = 0; w < TPB / 64; ++w) v += s_red[w][q];
            s[q] = v;
        }
        const double Np = fmax(s[5], 1.0);
        const double PN = fmax(s[6], 1.0);
        out[0] = (float)(s[0] / Np);
        out[1] = (float)(s[1] / Np);
        out[2] = (float)(s[2] / PN);
        out[3] = (float)(s[3] / PN);
        out[4] = (float)(s[4] / Np);
    }
}

extern "C" void kernel_launch(void* const* d_in, const int* in_sizes, int n_in,
                              void* d_out, int out_size, void* d_ws, size_t ws_size,
                              hipStream_t stream) {
    const float* loc     = (const float*)d_in[0];
    const float* conf    = (const float*)d_in[1];
    const float* ploc    = (const float*)d_in[2];
    const float* pconf   = (const float*)d_in[3];
    const float* center  = (const float*)d_in[4];
    const float* priors  = (const float*)d_in[5];
    const float* targets = (const float*)d_in[6];
    char* ws = (char*)d_ws;   // uses 24,576 bytes (partials only)

    dim3 grid(CBX, B_);
    msl_main<<<grid, TPB, 0, stream>>>(loc, conf, ploc, pconf, center, priors,
                                       targets, ws);
    msl_final<<<1, TPB, 0, stream>>>((const float*)ws, (float*)d_out);
}

// Round 7
// 154.317 us; speedup vs baseline: 1.0322x; 1.0322x over previous
//
#include <hip/hip_runtime.h>
#include <math.h>

#define B_      16
#define K_      200000
#define N_      40
#define TPB     256
#define CBX     128                          // chunks per batch
#define CHUNK   ((K_ + CBX - 1) / CBX)       // 1563 contiguous priors per block
#define NITER   ((CHUNK + TPB - 1) / TPB)    // 7 strided iterations per thread
#define NBLOCKS (CBX * B_)                   // 2048 (= 8 blocks/CU)
#define NE      (2 * N_)                     // 80 endpoints
#define NACC    7
#define PACC    8

// ws: [0, NBLOCKS*PACC*4) per-block partials (65,536 B). Nothing else.

typedef float v2f __attribute__((ext_vector_type(2)));

// asm loads: issue order is program order, results pinned in VGPRs,
// compiler cannot re-sink them (R5's failure) nor batch 24 of them (R3's).
__device__ __forceinline__ v2f ld2(const float* p) {
    v2f r;
    asm volatile("global_load_dwordx2 %0, %1, off" : "=v"(r) : "v"(p) : "memory");
    return r;
}
__device__ __forceinline__ float ld1(const float* p) {
    float r;
    asm volatile("global_load_dword %0, %1, off" : "=v"(r) : "v"(p) : "memory");
    return r;
}
// counted vmem wait + scheduling fence (rule #18)
#define WAITV(N) do { asm volatile("s_waitcnt vmcnt(" #N ")" ::: "memory"); \
                      __builtin_amdgcn_sched_barrier(0); } while (0)
// LDS-only barrier for table build (never drains vmcnt -> prologue prefetch
// stays in flight across it)
#define LBAR()   do { asm volatile("s_waitcnt lgkmcnt(0)" ::: "memory"); \
                      __builtin_amdgcn_sched_barrier(0); \
                      __builtin_amdgcn_s_barrier(); \
                      __builtin_amdgcn_sched_barrier(0); } while (0)

__device__ __forceinline__ void elem_accum(
    const float c, const float pl, const float pr,
    const float x0, const float x1,
    const float p0, const float p1,
    const float y0, const float y1,
    const float lg,
    const int base, const int end,
    const float* __restrict__ s_bp,
    const float4* __restrict__ s_tab,          // [0..79]=at, [80..160]=gap
    float& f0, float& f1, float& f2, float& f3,
    float& f4, float& f5, float& f6)
{
    const float EPS = 1.1920928955078125e-7f;  // FLT_EPSILON

    // ---- match: pos = #bp <= c; in-range bp are contiguous [base,end) ----
    int pos = base; bool eq = false;
    for (int i = base; i < end; ++i) {           // block-uniform bounds
        const float v = s_bp[i];                 // broadcast read
        pos += (v <= c) ? 1 : 0;
        eq  |= (v == c);
    }
    const int idx = eq ? (pos - 1) : (NE + pos);
    const float4 sg = s_tab[idx];

    const float tl = sg.x, tr = sg.y;
    const int conf_t = (int)sg.z;                // 0 when unmatched
    const float lt0 = (c - tl) * 256.0f;
    const float lt1 = (tr - c) * 256.0f;

    // ---- iou(loc, loc_t) ----
    const float inter = fminf(pl, lt0) + fminf(pr, lt1);
    const float uni   = pl + pr + (lt0 + lt1) - inter;
    const float iou   = __fdividef(inter, fmaxf(uni, EPS));
    const int pconf_t = (iou < 0.5f) ? 0 : conf_t;

    const float posf = (conf_t > 0) ? 1.0f : 0.0f;
    const float ppf  = (pconf_t > 0) ? 1.0f : 0.0f;

    // GIoU (pos only)
    const float ac   = fmaxf(pl, lt0) + fmaxf(pr, lt1);
    const float giou = iou - __fdividef(ac - uni, fmaxf(ac, EPS));
    f0 += (1.0f - giou) * posf;

    // prop loc L1 (prop-pos only)
    const float prop_w = pl + pr;
    const float rw = __fdividef(1.0f, 0.5f * prop_w);
    const float plt0 = (lt0 - pl) * rw;
    const float plt1 = (lt1 - pr) * rw;
    f2 += (fabsf(p0 - plt0) + fabsf(p1 - plt1)) * ppf;

    // centerness BCE (pos only)
    const float cur0 = 0.5f * prop_w * p0 + pl;
    const float cur1 = 0.5f * prop_w * p1 + pr;
    const float inter2 = fminf(cur0, lt0) + fminf(cur1, lt1);
    const float uni2   = cur0 + cur1 + (lt0 + lt1) - inter2;
    const float iou2   = fmaxf(__fdividef(inter2, fmaxf(uni2, EPS)), 0.0f);
    const float bce = fmaxf(lg, 0.0f) - lg * iou2
                      + __logf(1.0f + __expf(-fabsf(lg)));
    f4 += bce * posf;

    // focal on conf (all elements)
    {
        const float xt = conf_t ? x1 : x0;
        const float xo = conf_t ? x0 : x1;
        const float pt = __fdividef(1.0f, 1.0f + __expf(xo - xt)) + 1e-6f;
        const float al = conf_t ? 0.75f : 0.25f;
        const float om = 1.0f - pt;
        f1 += -om * om * al * __logf(pt);
    }
    // focal on prop_conf (all elements)
    {
        const float xt = pconf_t ? y1 : y0;
        const float xo = pconf_t ? y0 : y1;
        const float pt = __fdividef(1.0f, 1.0f + __expf(xo - xt)) + 1e-6f;
        const float al = pconf_t ? 0.75f : 0.25f;
        const float om = 1.0f - pt;
        f3 += -om * om * al * __logf(pt);
    }

    f5 += posf;
    f6 += ppf;
}

__global__ __launch_bounds__(TPB) void msl_main(
    const float* __restrict__ loc,     // (B,K,2)
    const float* __restrict__ conf,    // (B,K,2)
    const float* __restrict__ ploc,    // (B,K,2)
    const float* __restrict__ pconf,   // (B,K,2)
    const float* __restrict__ center,  // (B,K,1)
    const float* __restrict__ priors,  // (K,1)
    const float* __restrict__ targets, // (B,N,3)
    char* __restrict__ ws)
{
    __shared__ float  tl0[N_], tr0[N_], lb0[N_], ar0[N_];
    __shared__ float  stl[N_], str[N_], slb[N_];
    __shared__ float  s_ep[NE];
    __shared__ float  s_bp[NE];
    __shared__ float4 s_tab[2 * NE + 1];   // [0..79]=at, [80..160]=gap
    __shared__ int    s_cnt[4];
    __shared__ float  s_redf[TPB / 64][NACC];

    const int b  = blockIdx.y;
    const int cb = blockIdx.x;
    const int t  = threadIdx.x;
    const int kb = cb * CHUNK;
    const int kend = (kb + CHUNK < K_) ? kb + CHUNK : K_;

    const int bK  = b * K_;
    const int bK2 = bK * 2;

    // ======== phase 1: targets -> LDS (compiler drains its own vmcnt) =======
    if (t < N_) {
        const float* tg = targets + (b * N_ + t) * 3;
        const float tl = tg[0], tr = tg[1];
        tl0[t] = tl; tr0[t] = tr; lb0[t] = tg[2];
        ar0[t] = (tr - tl) * 256.0f;
    }

    // ---- issue iteration-0's 6 loads NOW (clamped addr; in flight across
    //      the whole table build -- LBAR never drains vmcnt) ----
    int  k  = kb + t;
    bool vc = (k < kend);
    const int kc0 = vc ? k : (kend - 1);
    v2f lc, cc_, pc_, qc; float gc, rc;
    {
        const int i2 = bK2 + kc0 * 2;
        lc  = ld2(loc   + i2);
        cc_ = ld2(conf  + i2);
        pc_ = ld2(ploc  + i2);
        qc  = ld2(pconf + i2);
        gc  = ld1(center + bK + kc0);
        rc  = ld1(priors + kc0);
    }

    LBAR();

    // phase 2: stable rank-sort segments by area (tie: orig index) + ep build
    if (t < N_) {
        const float an = ar0[t];
        int r = 0;
        #pragma unroll
        for (int m = 0; m < N_; ++m) {
            const float am = ar0[m];
            r += (am < an) || (am == an && m < t);
        }
        stl[r] = tl0[t]; str[r] = tr0[t]; slb[r] = lb0[t];
    }
    if (t < NE) s_ep[t] = (t < N_) ? tl0[t] : tr0[t - N_];
    LBAR();

    // phase 3: rank-sort endpoints
    if (t < NE) {
        const float v = s_ep[t];
        int r = 0;
        #pragma unroll
        for (int m = 0; m < NE; ++m) {
            const float vm = s_ep[m];
            r += (vm < v) || (vm == v && m < t);
        }
        s_bp[r] = v;
    }
    LBAR();

    // phase 4: winner tables + range ballot (one phase, one barrier)
    if (t < 128) {
        const float v = (t < NE) ? s_bp[t] : INFINITY;
        const float cmin = priors[kb];              // uniform -> s_load (lgkm)
        const float cmax = priors[kend - 1];
        const unsigned long long mlo = __ballot(v < cmin);
        const unsigned long long mhi = __ballot(v <= cmax);
        const int wv = t >> 6;
        if ((t & 63) == 0) {
            s_cnt[wv]     = __popcll(mlo);
            s_cnt[2 + wv] = __popcll(mhi);
        }
    }
    if (t < NE) {                                    // point winners
        const float v = s_bp[t];
        int w = N_;
        for (int s = N_ - 1; s >= 0; --s)
            w = (stl[s] <= v && v <= str[s]) ? s : w;
        const bool ok = (w < N_);
        const int si = ok ? w : 0;
        s_tab[t] = ok ? make_float4(stl[si], str[si], slb[si], 1.0f)
                      : make_float4(0.f, 0.f, 0.f, 0.f);
    }
    if (t >= 128 && t < 128 + NE + 1) {              // gap winners
        const int g = t - 128;
        const float a  = g ? s_bp[g - 1] : -INFINITY;
        const float bb = (g < NE) ? s_bp[g] : INFINITY;
        int w = N_;
        for (int s = N_ - 1; s >= 0; --s)
            w = (stl[s] <= a && bb <= str[s]) ? s : w;
        const bool ok = (w < N_);
        const int si = ok ? w : 0;
        s_tab[NE + g] = ok ? make_float4(stl[si], str[si], slb[si], 1.0f)
                           : make_float4(0.f, 0.f, 0.f, 0.f);
    }
    LBAR();

    const int base = s_cnt[0] + s_cnt[1];
    const int end  = s_cnt[2] + s_cnt[3];

    // ======== compute: asm-forced 1-deep prefetch, counted vmcnt ========
    float f0 = 0.f, f1 = 0.f, f2 = 0.f, f3 = 0.f, f4 = 0.f, f5 = 0.f, f6 = 0.f;

    #pragma unroll
    for (int it = 0; it < NITER; ++it) {
        const int  kn = k + TPB;
        v2f ln = {0.f, 0.f}, cn = {0.f, 0.f}, pn = {0.f, 0.f}, qn = {0.f, 0.f};
        float gn = 0.f, rn = 0.f;
        if (it < NITER - 1) {                 // compile-time uniform branch
            const int knc = (kn < kend) ? kn : (kend - 1);   // clamp: no
            const int i2n = bK2 + knc * 2;                   // divergent issue
            ln = ld2(loc   + i2n);
            cn = ld2(conf  + i2n);
            pn = ld2(ploc  + i2n);
            qn = ld2(pconf + i2n);
            gn = ld1(center + bK + knc);
            rn = ld1(priors + knc);
            WAITV(6);    // drain current's 6; keep next's 6 in flight
        } else {
            WAITV(0);    // last iteration: drain everything
        }
        if (vc)
            elem_accum(rc, lc.x, lc.y, cc_.x, cc_.y,
                       pc_.x, pc_.y, qc.x, qc.y, gc,
                       base, end, s_bp, s_tab,
                       f0, f1, f2, f3, f4, f5, f6);
        lc = ln; cc_ = cn; pc_ = pn; qc = qn; gc = gn; rc = rn;
        k = kn; vc = (kn < kend);
    }

    // ---- block reduction (f32 wave tree, f64 cross-wave) -> partials ----
    {
        float vals[NACC] = {f0, f1, f2, f3, f4, f5, f6};
        const int wave = t >> 6, lane = t & 63;
        #pragma unroll
        for (int q = 0; q < NACC; ++q) {
            float v = vals[q];
            #pragma unroll
            for (int off = 32; off > 0; off >>= 1)
                v += __shfl_down(v, off, 64);
            if (lane == 0) s_redf[wave][q] = v;
        }
    }
    __syncthreads();
    if (t == 0) {
        float* partials = (float*)ws;
        const int bid = b * CBX + cb;
        #pragma unroll
        for (int q = 0; q < NACC; ++q) {
            double s = 0.0;
            #pragma unroll
            for (int w2 = 0; w2 < TPB / 64; ++w2) s += (double)s_redf[w2][q];
            partials[bid * PACC + q] = (float)s;
        }
    }
}

__global__ __launch_bounds__(TPB) void msl_final(
    const float* __restrict__ partials, float* __restrict__ out)
{
    __shared__ double s_red[TPB / 64][NACC];
    double acc[NACC] = {0, 0, 0, 0, 0, 0, 0};
    for (int i = threadIdx.x; i < NBLOCKS; i += TPB) {
        #pragma unroll
        for (int q = 0; q < NACC; ++q)
            acc[q] += (double)partials[i * PACC + q];
    }
    const int wave = threadIdx.x >> 6, lane = threadIdx.x & 63;
    #pragma unroll
    for (int q = 0; q < NACC; ++q) {
        double v = acc[q];
        #pragma unroll
        for (int off = 32; off > 0; off >>= 1)
            v += __shfl_down(v, off, 64);
        if (lane == 0) s_red[wave][q] = v;
    }
    __syncthreads();
    if (threadIdx.x == 0) {
        double s[NACC];
        #pragma unroll
        for (int q = 0; q < NACC; ++q) {
            double v = 0.0;
            #pragma unroll
            for (int w = 0; w < TPB / 64; ++w) v += s_red[w][q];
            s[q] = v;
        }
        const double Np = fmax(s[5], 1.0);
        const double PN = fmax(s[6], 1.0);
        out[0] = (float)(s[0] / Np);
        out[1] = (float)(s[1] / Np);
        out[2] = (float)(s[2] / PN);
        out[3] = (float)(s[3] / PN);
        out[4] = (float)(s[4] / Np);
    }
}

extern "C" void kernel_launch(void* const* d_in, const int* in_sizes, int n_in,
                              void* d_out, int out_size, void* d_ws, size_t ws_size,
                              hipStream_t stream) {
    const float* loc     = (const float*)d_in[0];
    const float* conf    = (const float*)d_in[1];
    const float* ploc    = (const float*)d_in[2];
    const float* pconf   = (const float*)d_in[3];
    const float* center  = (const float*)d_in[4];
    const float* priors  = (const float*)d_in[5];
    const float* targets = (const float*)d_in[6];
    char* ws = (char*)d_ws;   // uses 65,536 bytes (partials only)

    dim3 grid(CBX, B_);
    msl_main<<<grid, TPB, 0, stream>>>(loc, conf, ploc, pconf, center, priors,
                                       targets, ws);
    msl_final<<<1, TPB, 0, stream>>>((const float*)ws, (float*)d_out);
}

// Round 8
// 152.209 us; speedup vs baseline: 1.0465x; 1.0138x over previous
//
#include <hip/hip_runtime.h>
#include <math.h>

#define B_      16
#define K_      200000
#define N_      40
#define TPB     256
#define CBX     128                          // chunks per batch
#define CHUNK   ((K_ + CBX - 1) / CBX)       // 1563 contiguous priors per block
#define NITER   ((CHUNK + TPB - 1) / TPB)    // 7 strided iterations per thread
#define NBLOCKS (CBX * B_)                   // 2048 (= 8 blocks/CU)
#define NE      (2 * N_)                     // 80 endpoints
#define NACC    7
#define PACC    8

// ws: [0, NBLOCKS*PACC*4) per-block partials (65,536 B). Nothing else.

typedef float v2f __attribute__((ext_vector_type(2)));

// saddr-form asm loads: SGPR-pair base + 32-bit VGPR byte offset.
// Issue order = program order; results pinned; minimal VGPR addressing cost.
__device__ __forceinline__ v2f ld2s(const float* sbase, unsigned off) {
    v2f r;
    asm volatile("global_load_dwordx2 %0, %1, %2"
                 : "=v"(r) : "v"(off), "s"(sbase) : "memory");
    return r;
}
__device__ __forceinline__ float ld1s(const float* sbase, unsigned off) {
    float r;
    asm volatile("global_load_dword %0, %1, %2"
                 : "=v"(r) : "v"(off), "s"(sbase) : "memory");
    return r;
}
// counted vmem wait + scheduling fence (rule #18)
#define WAITV(N) do { asm volatile("s_waitcnt vmcnt(" #N ")" ::: "memory"); \
                      __builtin_amdgcn_sched_barrier(0); } while (0)
// LDS-only barrier for table build (never drains vmcnt -> prologue prefetch
// stays in flight across it)
#define LBAR()   do { asm volatile("s_waitcnt lgkmcnt(0)" ::: "memory"); \
                      __builtin_amdgcn_sched_barrier(0); \
                      __builtin_amdgcn_s_barrier(); \
                      __builtin_amdgcn_sched_barrier(0); } while (0)

__device__ __forceinline__ void elem_accum(
    const float c, const float pl, const float pr,
    const float x0, const float x1,
    const float p0, const float p1,
    const float y0, const float y1,
    const float lg,
    const int base, const int end,
    const float* __restrict__ s_bp,
    const float4* __restrict__ s_tab,          // [0..79]=at, [80..160]=gap
    float& f0, float& f1, float& f2, float& f3,
    float& f4, float& f5, float& f6)
{
    const float EPS = 1.1920928955078125e-7f;  // FLT_EPSILON

    // ---- match: pos = #bp <= c; in-range bp are contiguous [base,end) ----
    int pos = base; bool eq = false;
    for (int i = base; i < end; ++i) {           // block-uniform bounds
        const float v = s_bp[i];                 // broadcast read
        pos += (v <= c) ? 1 : 0;
        eq  |= (v == c);
    }
    const int idx = eq ? (pos - 1) : (NE + pos);
    const float4 sg = s_tab[idx];

    const float tl = sg.x, tr = sg.y;
    const int conf_t = (int)sg.z;                // 0 when unmatched
    const float lt0 = (c - tl) * 256.0f;
    const float lt1 = (tr - c) * 256.0f;

    // ---- iou(loc, loc_t) ----
    const float inter = fminf(pl, lt0) + fminf(pr, lt1);
    const float uni   = pl + pr + (lt0 + lt1) - inter;
    const float iou   = __fdividef(inter, fmaxf(uni, EPS));
    const int pconf_t = (iou < 0.5f) ? 0 : conf_t;

    const float posf = (conf_t > 0) ? 1.0f : 0.0f;
    const float ppf  = (pconf_t > 0) ? 1.0f : 0.0f;

    // GIoU (pos only)
    const float ac   = fmaxf(pl, lt0) + fmaxf(pr, lt1);
    const float giou = iou - __fdividef(ac - uni, fmaxf(ac, EPS));
    f0 += (1.0f - giou) * posf;

    // prop loc L1 (prop-pos only)
    const float prop_w = pl + pr;
    const float rw = __fdividef(1.0f, 0.5f * prop_w);
    const float plt0 = (lt0 - pl) * rw;
    const float plt1 = (lt1 - pr) * rw;
    f2 += (fabsf(p0 - plt0) + fabsf(p1 - plt1)) * ppf;

    // centerness BCE (pos only)
    const float cur0 = 0.5f * prop_w * p0 + pl;
    const float cur1 = 0.5f * prop_w * p1 + pr;
    const float inter2 = fminf(cur0, lt0) + fminf(cur1, lt1);
    const float uni2   = cur0 + cur1 + (lt0 + lt1) - inter2;
    const float iou2   = fmaxf(__fdividef(inter2, fmaxf(uni2, EPS)), 0.0f);
    const float bce = fmaxf(lg, 0.0f) - lg * iou2
                      + __logf(1.0f + __expf(-fabsf(lg)));
    f4 += bce * posf;

    // focal on conf (all elements)
    {
        const float xt = conf_t ? x1 : x0;
        const float xo = conf_t ? x0 : x1;
        const float pt = __fdividef(1.0f, 1.0f + __expf(xo - xt)) + 1e-6f;
        const float al = conf_t ? 0.75f : 0.25f;
        const float om = 1.0f - pt;
        f1 += -om * om * al * __logf(pt);
    }
    // focal on prop_conf (all elements)
    {
        const float xt = pconf_t ? y1 : y0;
        const float xo = pconf_t ? y0 : y1;
        const float pt = __fdividef(1.0f, 1.0f + __expf(xo - xt)) + 1e-6f;
        const float al = pconf_t ? 0.75f : 0.25f;
        const float om = 1.0f - pt;
        f3 += -om * om * al * __logf(pt);
    }

    f5 += posf;
    f6 += ppf;
}

__global__ __launch_bounds__(TPB) void msl_main(
    const float* __restrict__ loc,     // (B,K,2)
    const float* __restrict__ conf,    // (B,K,2)
    const float* __restrict__ ploc,    // (B,K,2)
    const float* __restrict__ pconf,   // (B,K,2)
    const float* __restrict__ center,  // (B,K,1)
    const float* __restrict__ priors,  // (K,1)
    const float* __restrict__ targets, // (B,N,3)
    char* __restrict__ ws)
{
    __shared__ float  tl0[N_], tr0[N_], lb0[N_], ar0[N_];
    __shared__ float  stl[N_], str[N_], slb[N_];
    __shared__ float  s_ep[NE];
    __shared__ float  s_bp[NE];
    __shared__ float4 s_tab[2 * NE + 1];   // [0..79]=at, [80..160]=gap
    __shared__ int    s_cnt[4];
    __shared__ float  s_redf[TPB / 64][NACC];

    const int b  = blockIdx.y;
    const int cb = blockIdx.x;
    const int t  = threadIdx.x;
    const int kb = cb * CHUNK;
    const int kend = (kb + CHUNK < K_) ? kb + CHUNK : K_;

    const int bK  = b * K_;
    const int bK2 = bK * 2;

    // ======== phase 1: targets -> LDS (its vmcnt wait lands BEFORE the
    //          asm prefetch below; LDS stores complete first) ========
    if (t < N_) {
        const float* tg = targets + (b * N_ + t) * 3;
        const float tl = tg[0], tr = tg[1];
        tl0[t] = tl; tr0[t] = tr; lb0[t] = tg[2];
        ar0[t] = (tr - tl) * 256.0f;
    }
    __builtin_amdgcn_sched_barrier(0);

    // ---- issue items 0 AND 1 now (12 loads in flight across the whole
    //      table build -- LBAR never drains vmcnt) ----
    int  k  = kb + t;
    bool vc = (k < kend);
    v2f lA, cA, pA, qA; float gA, rA;      // current item
    v2f lB, cB, pB, qB; float gB, rB;      // next item
    {
        const int k0 = vc ? k : (kend - 1);
        const unsigned o4 = (unsigned)(bK2 + k0 * 2) * 4u;
        const unsigned oc = (unsigned)(bK + k0) * 4u;
        const unsigned op = (unsigned)k0 * 4u;
        lA = ld2s(loc, o4);  cA = ld2s(conf, o4);
        pA = ld2s(ploc, o4); qA = ld2s(pconf, o4);
        gA = ld1s(center, oc); rA = ld1s(priors, op);
    }
    {
        const int k1 = k + TPB;
        const int kc = (k1 < kend) ? k1 : (kend - 1);
        const unsigned o4 = (unsigned)(bK2 + kc * 2) * 4u;
        const unsigned oc = (unsigned)(bK + kc) * 4u;
        const unsigned op = (unsigned)kc * 4u;
        lB = ld2s(loc, o4);  cB = ld2s(conf, o4);
        pB = ld2s(ploc, o4); qB = ld2s(pconf, o4);
        gB = ld1s(center, oc); rB = ld1s(priors, op);
    }

    LBAR();

    // phase 2: stable rank-sort segments by area (tie: orig index) + ep build
    if (t < N_) {
        const float an = ar0[t];
        int r = 0;
        #pragma unroll
        for (int m = 0; m < N_; ++m) {
            const float am = ar0[m];
            r += (am < an) || (am == an && m < t);
        }
        stl[r] = tl0[t]; str[r] = tr0[t]; slb[r] = lb0[t];
    }
    if (t < NE) s_ep[t] = (t < N_) ? tl0[t] : tr0[t - N_];
    LBAR();

    // phase 3: rank-sort endpoints
    if (t < NE) {
        const float v = s_ep[t];
        int r = 0;
        #pragma unroll
        for (int m = 0; m < NE; ++m) {
            const float vm = s_ep[m];
            r += (vm < v) || (vm == v && m < t);
        }
        s_bp[r] = v;
    }
    LBAR();

    // phase 4: winner tables + range ballot (one phase, one barrier)
    if (t < 128) {
        const float v = (t < NE) ? s_bp[t] : INFINITY;
        const float cmin = priors[kb];              // uniform -> s_load (lgkm)
        const float cmax = priors[kend - 1];
        const unsigned long long mlo = __ballot(v < cmin);
        const unsigned long long mhi = __ballot(v <= cmax);
        const int wv = t >> 6;
        if ((t & 63) == 0) {
            s_cnt[wv]     = __popcll(mlo);
            s_cnt[2 + wv] = __popcll(mhi);
        }
    }
    if (t < NE) {                                    // point winners
        const float v = s_bp[t];
        int w = N_;
        for (int s = N_ - 1; s >= 0; --s)
            w = (stl[s] <= v && v <= str[s]) ? s : w;
        const bool ok = (w < N_);
        const int si = ok ? w : 0;
        s_tab[t] = ok ? make_float4(stl[si], str[si], slb[si], 1.0f)
                      : make_float4(0.f, 0.f, 0.f, 0.f);
    }
    if (t >= 128 && t < 128 + NE + 1) {              // gap winners
        const int g = t - 128;
        const float a  = g ? s_bp[g - 1] : -INFINITY;
        const float bb = (g < NE) ? s_bp[g] : INFINITY;
        int w = N_;
        for (int s = N_ - 1; s >= 0; --s)
            w = (stl[s] <= a && bb <= str[s]) ? s : w;
        const bool ok = (w < N_);
        const int si = ok ? w : 0;
        s_tab[NE + g] = ok ? make_float4(stl[si], str[si], slb[si], 1.0f)
                           : make_float4(0.f, 0.f, 0.f, 0.f);
    }
    LBAR();

    const int base = s_cnt[0] + s_cnt[1];
    const int end  = s_cnt[2] + s_cnt[3];

    // ======== compute: asm-forced 2-deep prefetch, counted vmcnt ========
    float f0 = 0.f, f1 = 0.f, f2 = 0.f, f3 = 0.f, f4 = 0.f, f5 = 0.f, f6 = 0.f;

    #pragma unroll
    for (int it = 0; it < NITER; ++it) {
        v2f lC = {0.f, 0.f}, cC = {0.f, 0.f}, pC = {0.f, 0.f}, qC = {0.f, 0.f};
        float gC = 0.f, rC = 0.f;
        if (it + 2 < NITER) {                 // compile-time uniform branch
            const int kn2 = k + 2 * TPB;
            const int knc = (kn2 < kend) ? kn2 : (kend - 1);   // clamp: no
            const unsigned o4 = (unsigned)(bK2 + knc * 2) * 4u;// divergent issue
            const unsigned oc = (unsigned)(bK + knc) * 4u;
            const unsigned op = (unsigned)knc * 4u;
            lC = ld2s(loc, o4);  cC = ld2s(conf, o4);
            pC = ld2s(ploc, o4); qC = ld2s(pconf, o4);
            gC = ld1s(center, oc); rC = ld1s(priors, op);
            WAITV(12);   // drain current's 6; keep 2 items (12 loads) in flight
        } else if (it + 2 == NITER) {
            WAITV(6);    // drain current's 6; keep last item's 6 in flight
        } else {
            WAITV(0);    // final iteration: drain everything
        }
        if (vc)
            elem_accum(rA, lA.x, lA.y, cA.x, cA.y,
                       pA.x, pA.y, qA.x, qA.y, gA,
                       base, end, s_bp, s_tab,
                       f0, f1, f2, f3, f4, f5, f6);
        // rotate register sets (pure SSA renaming under full unroll)
        lA = lB; cA = cB; pA = pB; qA = qB; gA = gB; rA = rB;
        lB = lC; cB = cC; pB = pC; qB = qC; gB = gC; rB = rC;
        k += TPB; vc = (k < kend);
    }

    // ---- block reduction (f32 wave tree, f64 cross-wave) -> partials ----
    {
        float vals[NACC] = {f0, f1, f2, f3, f4, f5, f6};
        const int wave = t >> 6, lane = t & 63;
        #pragma unroll
        for (int q = 0; q < NACC; ++q) {
            float v = vals[q];
            #pragma unroll
            for (int off = 32; off > 0; off >>= 1)
                v += __shfl_down(v, off, 64);
            if (lane == 0) s_redf[wave][q] = v;
        }
    }
    __syncthreads();
    if (t == 0) {
        float* partials = (float*)ws;
        const int bid = b * CBX + cb;
        #pragma unroll
        for (int q = 0; q < NACC; ++q) {
            double s = 0.0;
            #pragma unroll
            for (int w2 = 0; w2 < TPB / 64; ++w2) s += (double)s_redf[w2][q];
            partials[bid * PACC + q] = (float)s;
        }
    }
}

__global__ __launch_bounds__(TPB) void msl_final(
    const float* __restrict__ partials, float* __restrict__ out)
{
    __shared__ double s_red[TPB / 64][NACC];
    double acc[NACC] = {0, 0, 0, 0, 0, 0, 0};
    for (int i = threadIdx.x; i < NBLOCKS; i += TPB) {
        #pragma unroll
        for (int q = 0; q < NACC; ++q)
            acc[q] += (double)partials[i * PACC + q];
    }
    const int wave = threadIdx.x >> 6, lane = threadIdx.x & 63;
    #pragma unroll
    for (int q = 0; q < NACC; ++q) {
        double v = acc[q];
        #pragma unroll
        for (int off = 32; off > 0; off >>= 1)
            v += __shfl_down(v, off, 64);
        if (lane == 0) s_red[wave][q] = v;
    }
    __syncthreads();
    if (threadIdx.x == 0) {
        double s[NACC];
        #pragma unroll
        for (int q = 0; q < NACC; ++q) {
            double v = 0.0;
            #pragma unroll
            for (int w = 0; w < TPB / 64; ++w) v += s_red[w][q];
            s[q] = v;
        }
        const double Np = fmax(s[5], 1.0);
        const double PN = fmax(s[6], 1.0);
        out[0] = (float)(s[0] / Np);
        out[1] = (float)(s[1] / Np);
        out[2] = (float)(s[2] / PN);
        out[3] = (float)(s[3] / PN);
        out[4] = (float)(s[4] / Np);
    }
}

extern "C" void kernel_launch(void* const* d_in, const int* in_sizes, int n_in,
                              void* d_out, int out_size, void* d_ws, size_t ws_size,
                              hipStream_t stream) {
    const float* loc     = (const float*)d_in[0];
    const float* conf    = (const float*)d_in[1];
    const float* ploc    = (const float*)d_in[2];
    const float* pconf   = (const float*)d_in[3];
    const float* center  = (const float*)d_in[4];
    const float* priors  = (const float*)d_in[5];
    const float* targets = (const float*)d_in[6];
    char* ws = (char*)d_ws;   // uses 65,536 bytes (partials only)

    dim3 grid(CBX, B_);
    msl_main<<<grid, TPB, 0, stream>>>(loc, conf, ploc, pconf, center, priors,
                                       targets, ws);
    msl_final<<<1, TPB, 0, stream>>>((const float*)ws, (float*)d_out);
}